// Round 1
// baseline (200.628 us; speedup 1.0000x reference)
//
#include <hip/hip_runtime.h>
#include <stdint.h>

typedef __attribute__((ext_vector_type(8)))  short  short8;
typedef __attribute__((ext_vector_type(8)))  __bf16 bf16x8;
typedef __attribute__((ext_vector_type(16))) float  floatx16;
typedef __attribute__((ext_vector_type(4)))  float  floatx4;
typedef __attribute__((ext_vector_type(2)))  float  float2v;
typedef __attribute__((ext_vector_type(4)))  uint32_t uint4v;

union Frag { short8 s; bf16x8 v; uint4v d; };
union FU   { float f; uint32_t u; };

// round-to-nearest-even f32 -> bf16 (setup only)
__device__ __forceinline__ short f2bf(float f) {
    FU x; x.f = f;
    uint32_t r = x.u + 0x7fffu + ((x.u >> 16) & 1u);
    return (short)(r >> 16);
}

// pack two f32 -> bf16x2 dword, round-half-up: 2 adds + 1 v_perm
__device__ __forceinline__ uint32_t pack_bf2(float lo, float hi) {
    FU a, b; a.f = lo; b.f = hi;
    return __builtin_amdgcn_perm(b.u + 0x8000u, a.u + 0x8000u, 0x07060302u);
}

__device__ __forceinline__ float fexp2(float x) { return __builtin_amdgcn_exp2f(x); }
__device__ __forceinline__ float frcp(float x)  { return __builtin_amdgcn_rcpf(x); }
__device__ __forceinline__ float fclamp(float x, float lo, float hi) {
#if __has_builtin(__builtin_amdgcn_fmed3f)
    return __builtin_amdgcn_fmed3f(x, lo, hi);
#else
    return fminf(fmaxf(x, lo), hi);
#endif
}

// T = exp2(clamp(arg)) + 1 for a pair of accumulator values
__device__ __forceinline__ float2v tpair(float a, float b) {
    float2v t;
    t.x = fexp2(fclamp(a, -30.0f, 30.0f));
    t.y = fexp2(fclamp(b, -30.0f, 30.0f));
    return t + 1.0f;
}

// y[b] = a0 + sum_k bk[k] * tanh(ck[k,:].z[b,:] + dk[k])
//
// D = mfma_32x32x16_bf16(A=s*ck, B=z, C=s*dk) -> D[node][row] = s*(dot+dk),
// s = 2*log2(e); col(lane&31)=batch row, node=(reg&3)+8*(reg>>2)+4*(lane>>5).
// tanh(t) = 1 - 2/(exp2(s*t)+1); 4-way shared denominator:
//   b0/t0+..+b3/t3 = [(b0t1+b1t0)t2t3 + (b2t3+b3t2)t0t1] * rcp(t0t1t2t3)
//
// R10 (from R9 counters: VALUBusy=32%, MfmaUtil=2%, HBM=11.6%, Occ=19%,
// VGPR=104 -> 4 waves/SIMD: latency-bound, nothing saturated):
//  - Kill 64 persistent VGPRs of per-wave constants: cinit (S*dk, MFMA-C
//    order) and nb (-2*bk pairs) live in a 768B LDS table built once per
//    block; every read is same-address broadcast within a 32-lane half
//    (conflict-free). MFMA C operand is ds_read directly into the D regs.
//  - Half-split: process nodes 0-31 (acc0) fully before the nodes 32-63
//    MFMA -> accumulator peak is 16 regs, not 32. float2 shared-denominator
//    lanes re-paired WITHIN a half: group-a = regs r..r+3, group-b = r+4..r+7.
//  - z pipeline depth 4 -> 3 (-8 VGPRs); residency TLP covers the rest.
//  - base = a0 + sum(bk): once per block (wave-0 shfl reduce -> LDS).
// Target: VGPR <= 84 -> 6+ waves/SIMD, all work resident in ~1 round.
__global__ __launch_bounds__(256) void mave_kernel(
    const float* __restrict__ z,
    const float* __restrict__ a0,
    const float* __restrict__ bk,
    const float* __restrict__ ck,
    const float* __restrict__ dk,
    float* __restrict__ out,
    int ntiles)
{
    const int lane = threadIdx.x & 63;
    const int m    = lane & 31;
    const int g    = lane >> 5;
    const float S  = 2.885390081777927f;  // 2*log2(e)

    // ---- per-block constant tables in LDS (broadcast reads) ----
    __shared__ __align__(16) float   cinitL[2][2][16];    // [g][h][reg]
    __shared__ __align__(16) float2v nbL[2][2][2][4];     // [g][h][rg][j]
    __shared__ float baseL;

    if (threadIdx.x < 64) {
        const int t = threadIdx.x;
        {   // 64 entries: (g,h,reg)
            const int gg = t >> 5, hh = (t >> 4) & 1, r = t & 15;
            const int n  = (r & 3) + 8 * (r >> 2) + 4 * gg + 32 * hh;
            cinitL[gg][hh][r] = S * dk[n];
        }
        if (t < 32) {  // 32 entries: (g,h,rg,j); pair = (reg 8rg+j, reg 8rg+4+j)
            const int gg = t >> 4, hh = (t >> 3) & 1, rg = (t >> 2) & 1, j = t & 3;
            const int rl = 8 * rg + j,     rh = 8 * rg + 4 + j;
            const int nl = (rl & 3) + 8 * (rl >> 2) + 4 * gg + 32 * hh;
            const int nh = (rh & 3) + 8 * (rh >> 2) + 4 * gg + 32 * hh;
            float2v nb; nb.x = -2.0f * bk[nl]; nb.y = -2.0f * bk[nh];
            nbL[gg][hh][rg][j] = nb;
        }
        float bv = bk[t];
        #pragma unroll
        for (int d = 1; d < 64; d <<= 1) bv += __shfl_xor(bv, d, 64);
        if (t == 0) baseL = a0[0] + bv;
    }
    __syncthreads();

    const int wid   = (int)((blockIdx.x * blockDim.x + threadIdx.x) >> 6);
    const int tile0 = wid * 8;
    if (tile0 >= ntiles) return;
    const int tlast = ntiles - 1;

    const float* zp = z + (size_t)m * 16 + g * 8;

    // ---- issue depth-3 z loads FIRST (6x dwordx4 in flight) ----
    floatx4 zb[3][2];
    #pragma unroll
    for (int i = 0; i < 3; ++i) {
        int ti = tile0 + i; if (ti > tlast) ti = tlast;   // s_min, benign
        const float* q = zp + (size_t)ti * 512;
        zb[i][0] = *(const floatx4*)q;
        zb[i][1] = *(const floatx4*)(q + 4);
    }

    // ---- preamble overlaps the z-load latency ----
    Frag af[2];
    {
        const float* c0 = ck + m * 16 + g * 8;
        #pragma unroll
        for (int e = 0; e < 8; ++e) {
            af[0].s[e] = f2bf(c0[e] * S);
            af[1].s[e] = f2bf(c0[32 * 16 + e] * S);
        }
    }

    // lane-g base pointers into the LDS tables (imm offsets for h/rg/quad)
    const floatx4* cqg = (const floatx4*)&cinitL[g][0][0];  // quad h*4+q
    const floatx4* nqg = (const floatx4*)&nbL[g][0][0][0];  // quad h*4+rg*2+k

    // ---- 8 tiles, straight-line, rolling refill at distance 3 ----
    float yv[8];
    #pragma unroll
    for (int i = 0; i < 8; ++i) {
        const int s3 = i % 3;   // compile-time (fully unrolled)

        Frag bfr;
        bfr.d[0] = pack_bf2(zb[s3][0].x, zb[s3][0].y);
        bfr.d[1] = pack_bf2(zb[s3][0].z, zb[s3][0].w);
        bfr.d[2] = pack_bf2(zb[s3][1].x, zb[s3][1].y);
        bfr.d[3] = pack_bf2(zb[s3][1].z, zb[s3][1].w);

        if (i + 3 < 8) {                  // compile-time guard (unrolled)
            int ti = tile0 + i + 3; if (ti > tlast) ti = tlast;
            const float* q = zp + (size_t)ti * 512;
            zb[s3][0] = *(const floatx4*)q;
            zb[s3][1] = *(const floatx4*)(q + 4);
        }

        float ya = 0.0f;
        #pragma unroll
        for (int h = 0; h < 2; ++h) {
            // C operand fresh from LDS; D overwrites it in place
            union { floatx16 v; floatx4 q[4]; } C;
            C.q[0] = cqg[h * 4 + 0]; C.q[1] = cqg[h * 4 + 1];
            C.q[2] = cqg[h * 4 + 2]; C.q[3] = cqg[h * 4 + 3];
            floatx16 acc = __builtin_amdgcn_mfma_f32_32x32x16_bf16(
                af[h].v, bfr.v, C.v, 0, 0, 0);

            float2v Y = {0.0f, 0.0f};
            #pragma unroll
            for (int rg = 0; rg < 2; ++rg) {
                union { floatx4 q; float2v p[2]; } NA, NB;
                NA.q = nqg[h * 4 + rg * 2 + 0];   // nb[j=0], nb[j=1]
                NB.q = nqg[h * 4 + rg * 2 + 1];   // nb[j=2], nb[j=3]
                float2v T0 = tpair(acc[8 * rg + 0], acc[8 * rg + 4]);
                float2v T1 = tpair(acc[8 * rg + 1], acc[8 * rg + 5]);
                float2v T2 = tpair(acc[8 * rg + 2], acc[8 * rg + 6]);
                float2v T3 = tpair(acc[8 * rg + 3], acc[8 * rg + 7]);
                float2v P01 = T0 * T1, P23 = T2 * T3, P = P01 * P23;
                float2v R; R.x = frcp(P.x); R.y = frcp(P.y);
                float2v n01 = NA.p[0] * T1 + NA.p[1] * T0;
                float2v n23 = NB.p[0] * T3 + NB.p[1] * T2;
                float2v num = n01 * P23 + n23 * P01;
                Y += num * R;
            }
            ya += Y.x + Y.y;
        }
        yv[i] = ya;
    }

    // ---- batched cross-half merge (one lgkm drain) + stores ----
    const float base = baseL;
    float ov[8];
    #pragma unroll
    for (int i = 0; i < 8; ++i) ov[i] = __shfl_xor(yv[i], 32, 64);
    if (g == 0) {
        #pragma unroll
        for (int i = 0; i < 8; ++i) {
            int ti = tile0 + i; if (ti > tlast) ti = tlast;
            out[(size_t)ti * 32 + m] = base + yv[i] + ov[i];
        }
    }
}

extern "C" void kernel_launch(void* const* d_in, const int* in_sizes, int n_in,
                              void* d_out, int out_size, void* d_ws, size_t ws_size,
                              hipStream_t stream) {
    const float* z  = (const float*)d_in[0];
    const float* a0 = (const float*)d_in[1];
    const float* bk = (const float*)d_in[2];
    const float* ck = (const float*)d_in[3];
    const float* dk = (const float*)d_in[4];
    float* out = (float*)d_out;

    const int B      = in_sizes[0] / 16;       // z is [B,16]
    const int ntiles = B / 32;                 // 32 batch rows per wave-tile

    // 8 tiles/wave, 4 waves/block -> 32 tiles/block; 2048 blocks at B=2M
    const int blocks = (ntiles + 31) / 32;
    hipLaunchKernelGGL(mave_kernel, dim3(blocks), dim3(256), 0, stream,
                       z, a0, bk, ck, dk, out, ntiles);
}